// Round 7
// baseline (437.352 us; speedup 1.0000x reference)
//
#include <hip/hip_runtime.h>
#include <hip/hip_bf16.h>

typedef unsigned short u16;
typedef unsigned int u32;
typedef __attribute__((ext_vector_type(8))) short bf16x8;   // 8 bf16 in 4 VGPRs
typedef __attribute__((ext_vector_type(4))) float f32x4;
typedef __attribute__((ext_vector_type(16))) float f32x16;

#define GLDS16(gptr, lptr)                                                        \
  __builtin_amdgcn_global_load_lds(                                               \
      (__attribute__((address_space(1))) const void*)(gptr),                      \
      (__attribute__((address_space(3))) void*)(lptr), 16, 0, 0)

__device__ __forceinline__ u16 f2bf(float f) {
  union { float f; unsigned u; } v; v.f = f;
  unsigned r = v.u + 0x7fffu + ((v.u >> 16) & 1u);   // RNE, finite inputs only
  return (u16)(r >> 16);
}

__device__ __forceinline__ u32 pack_bf2(float a, float b) {
  union { __hip_bfloat162 h2; u32 u; } v;
  v.h2 = __float22bfloat162_rn(make_float2(a, b));
  return v.u;
}

// ---------------- fused prep: x-cast | Wout-cast | W_eff/b_eff ----------------
__global__ void k_prep(const float* __restrict__ x, const float* __restrict__ Wqkv,
                       const float* __restrict__ Wlora, const float* __restrict__ blora,
                       const float* __restrict__ Aq, const float* __restrict__ Bq,
                       const float* __restrict__ Av, const float* __restrict__ Bv,
                       const float* __restrict__ Wout,
                       u16* __restrict__ Xb, u16* __restrict__ Weff,
                       float* __restrict__ beff, u16* __restrict__ Woutb) {
  const int bid = blockIdx.x, tid = threadIdx.x;
  if (bid < 8192) {                       // x: 8192*1024 f32 -> bf16, float4-wide
    int i = bid * 256 + tid;
    float4 f = reinterpret_cast<const float4*>(x)[i];
    ushort4 u;
    u.x = f2bf(f.x); u.y = f2bf(f.y); u.z = f2bf(f.z); u.w = f2bf(f.w);
    reinterpret_cast<ushort4*>(Xb)[i] = u;
  } else if (bid < 9216) {                // Wout: 1024*1024
    int i = (bid - 8192) * 256 + tid;
    float4 f = reinterpret_cast<const float4*>(Wout)[i];
    ushort4 u;
    u.x = f2bf(f.x); u.y = f2bf(f.y); u.z = f2bf(f.z); u.w = f2bf(f.w);
    reinterpret_cast<ushort4*>(Woutb)[i] = u;
  } else {                                // W_eff
    int idx = (bid - 9216) * 256 + tid;   // < 3072*1024
    int o = idx >> 10, c = idx & 1023;
    float w = Wqkv[idx];
    if (o < 1024) {
      float lr = 0.f;
#pragma unroll
      for (int r = 0; r < 8; ++r) lr += Bq[o * 8 + r] * Aq[r * 1024 + c];
      w += Wlora[idx] + 0.125f * lr;
    } else if (o >= 2048) {
      int o2 = o - 2048;
      float lr = 0.f;
#pragma unroll
      for (int r = 0; r < 8; ++r) lr += Bv[o2 * 8 + r] * Av[r * 1024 + c];
      w += Wlora[idx] + 0.125f * lr;
    }
    Weff[idx] = f2bf(w);
    if (c == 0) beff[o] = (o < 1024 || o >= 2048) ? blora[o] : 0.f;
  }
}

// ---------------- GEMM1: Y[8192][3072] = Xb @ Weff^T + beff ----------------
// q slice scaled by log2(e)/8 (softmax scale folded, exp2-domain for k_attn).
__global__ __launch_bounds__(256, 3)
void k_gemm_qkv(const u16* __restrict__ Xb, const u16* __restrict__ Weff,
                const float* __restrict__ beff, u16* __restrict__ Y) {
  __shared__ u16 As[128 * 32], Bs[128 * 32];
  const int tid = threadIdx.x, lane = tid & 63, wave = tid >> 6;
  const int lr = lane & 15, lg = lane >> 4;
  const int wr = wave >> 1, wc = wave & 1;
  // bijective XCD swizzle over 1536 workgroups (1536 % 8 == 0)
  const int wg = blockIdx.x + 24 * blockIdx.y;
  const int swz = (wg & 7) * 192 + (wg >> 3);
  const int m0 = (swz / 24) * 128, n0 = (swz % 24) * 128;
  f32x4 acc[4][4] = {};

  for (int k0 = 0; k0 < 1024; k0 += 32) {
#pragma unroll
    for (int i = 0; i < 2; ++i) {
      int gc = ((tid & 3) ^ ((tid >> 2) & 3)) << 3;
      GLDS16(Xb + (size_t)(m0 + i * 64 + (tid >> 2)) * 1024 + k0 + gc, As + i * 2048 + wave * 512);
      GLDS16(Weff + (size_t)(n0 + i * 64 + (tid >> 2)) * 1024 + k0 + gc, Bs + i * 2048 + wave * 512);
    }
    __syncthreads();
    bf16x8 af[4], bfr[4];
#pragma unroll
    for (int t = 0; t < 4; ++t) {
      int ch = ((lg ^ (lr & 3)) & 3) << 3;
      af[t]  = *reinterpret_cast<const bf16x8*>(As + (wr * 64 + t * 16 + lr) * 32 + ch);
      bfr[t] = *reinterpret_cast<const bf16x8*>(Bs + (wc * 64 + t * 16 + lr) * 32 + ch);
    }
#pragma unroll
    for (int mi = 0; mi < 4; ++mi)
#pragma unroll
      for (int ni = 0; ni < 4; ++ni)
        acc[mi][ni] = __builtin_amdgcn_mfma_f32_16x16x32_bf16(af[mi], bfr[ni], acc[mi][ni], 0, 0, 0);
    __syncthreads();
  }

#pragma unroll
  for (int mi = 0; mi < 4; ++mi) {
    int row = m0 + wr * 64 + mi * 16 + (lg << 2);
#pragma unroll
    for (int ni = 0; ni < 4; ++ni) {
      int col = n0 + wc * 64 + ni * 16 + lr;
      float bias = beff[col];
#pragma unroll
      for (int j = 0; j < 4; ++j) {
        float v = acc[mi][ni][j] + bias;
        if (col < 1024) v *= 0.18033688011112042f;  // log2(e)/8: softmax scale + exp2 domain
        Y[(size_t)(row + j) * 3072 + col] = f2bf(v);
      }
    }
  }
}

// ---------------- Vt transpose: Vt[(b*16+h)*64+d][n] = Y[b*2048+n][2048+h*64+d] ----------------
__global__ __launch_bounds__(256)
void k_vtrans(const u16* __restrict__ Y, u16* __restrict__ Vt) {
  __shared__ u16 Ls[64 * 65];
  const int t = threadIdx.x;
  const int bh = blockIdx.y, b = bh >> 4, h = bh & 15;
  const int n0 = blockIdx.x * 64;
#pragma unroll
  for (int c = 0; c < 2; ++c) {
    int idx = c * 256 + t;
    int nl = idx >> 3, d0 = (idx & 7) * 8;
    bf16x8 val = *reinterpret_cast<const bf16x8*>(
        Y + (size_t)(b * 2048 + n0 + nl) * 3072 + 2048 + h * 64 + d0);
#pragma unroll
    for (int j = 0; j < 8; ++j) Ls[(d0 + j) * 65 + nl] = (u16)val[j];
  }
  __syncthreads();
#pragma unroll
  for (int c = 0; c < 2; ++c) {
    int idx = c * 256 + t;
    int dl = idx >> 3, nn = (idx & 7) * 8;
    bf16x8 outv;
#pragma unroll
    for (int j = 0; j < 8; ++j) outv[j] = (short)Ls[dl * 65 + nn + j];
    *reinterpret_cast<bf16x8*>(Vt + (size_t)(bh * 64 + dl) * 2048 + n0 + nn) = outv;
  }
}

// ---------------- flash attention: 32x32 swapped QK^T, P in-register, unrolled dbuf ----------------
__global__ __launch_bounds__(256, 4)
void k_attn(const u16* __restrict__ Y, const u16* __restrict__ Vt, u16* __restrict__ Oa) {
  __shared__ u16 Ks[2][64 * 64], Vs[2][64 * 64];
  const int tid = threadIdx.x, lane = tid & 63, wave = tid >> 6;
  const int b = blockIdx.y >> 4, h = blockIdx.y & 15;
  const int q0 = blockIdx.x * 128;
  const int l31 = lane & 31, hi = lane >> 5;
  const size_t bq = (size_t)b * 2048;
  const size_t bv = (size_t)b * 1024 + h * 64;
  const int hc = h * 64;

  // Q B-frags: n=qrow=wave*32+l31, k = d = ks*16 + 8*hi + j  (Q pre-scaled log2e/8)
  bf16x8 qb[4];
  {
    const u16* yr = Y + (bq + q0 + wave * 32 + l31) * 3072 + hc + hi * 8;
#pragma unroll
    for (int ks = 0; ks < 4; ++ks)
      qb[ks] = *reinterpret_cast<const bf16x8*>(yr + ks * 16);
  }

  float m_run = -1e30f, l_run = 0.f;
  f32x16 oacc[2] = {};

  const int sr = tid >> 3, sc = tid & 7;
  auto stage = [&](int key0, int bb) {
#pragma unroll
    for (int i = 0; i < 2; ++i) {
      int r = i * 32 + sr;
      int gc = (sc ^ (r & 7)) << 3;
      GLDS16(Y + (bq + key0 + r) * 3072 + 1024 + hc + gc, &Ks[bb][i * 2048 + wave * 512]);
      GLDS16(Vt + (bv + r) * 2048 + key0 + gc,            &Vs[bb][i * 2048 + wave * 512]);
    }
  };

  auto compute = [&](const u16* __restrict__ Kt, const u16* __restrict__ Vti) {
    bf16x8 kb[2][4], vb[2][4];
#pragma unroll
    for (int t = 0; t < 2; ++t) {
      const u16* kbase = Kt + (t * 32 + l31) * 64;
      int rx = (t * 32 + l31) & 7;
#pragma unroll
      for (int ks = 0; ks < 4; ++ks)
        kb[t][ks] = *reinterpret_cast<const bf16x8*>(kbase + (((ks * 2 + hi) ^ rx) << 3));
    }
#pragma unroll
    for (int dt = 0; dt < 2; ++dt) {
      const u16* vbase = Vti + (dt * 32 + l31) * 64;
      int rx = (dt * 32 + l31) & 7;
#pragma unroll
      for (int ks = 0; ks < 4; ++ks)
        vb[dt][ks] = *reinterpret_cast<const bf16x8*>(vbase + (((ks * 2 + hi) ^ rx) << 3));
    }

    f32x16 p4[2] = {};
    __builtin_amdgcn_s_setprio(1);
#pragma unroll
    for (int t = 0; t < 2; ++t)
#pragma unroll
      for (int ks = 0; ks < 4; ++ks)
        p4[t] = __builtin_amdgcn_mfma_f32_32x32x16_bf16(kb[t][ks], qb[ks], p4[t], 0, 0, 0);
    __builtin_amdgcn_s_setprio(0);

    // max over 32 in-lane scores: max3-friendly chain (16 ops), then cross-half
    float tmax = fmaxf(p4[0][0], p4[0][1]);
#pragma unroll
    for (int r = 2; r < 16; r += 2) tmax = fmaxf(fmaxf(tmax, p4[0][r]), p4[0][r + 1]);
#pragma unroll
    for (int r = 0; r < 16; r += 2) tmax = fmaxf(fmaxf(tmax, p4[1][r]), p4[1][r + 1]);
    tmax = fmaxf(tmax, __shfl_xor(tmax, 32));

    // defer-max (T13, base-2, THR=11)
    if (__any(tmax > m_run + 11.0f)) {
      float mnew = fmaxf(m_run, tmax);
      float alpha = __builtin_amdgcn_exp2f(m_run - mnew);
      m_run = mnew;
      l_run *= alpha;
#pragma unroll
      for (int r = 0; r < 16; ++r) {
        float ab = __shfl(alpha, (r & 3) + 8 * (r >> 2) + 4 * hi);
        oacc[0][r] *= ab;
        oacc[1][r] *= ab;
      }
    }

    // P = exp2(S - m); pack to bf16 pairs; row-sum
    float rs = 0.f;
    u32 w[2][4][2];
#pragma unroll
    for (int t = 0; t < 2; ++t)
#pragma unroll
      for (int g = 0; g < 4; ++g) {
        float e0 = __builtin_amdgcn_exp2f(p4[t][4 * g + 0] - m_run);
        float e1 = __builtin_amdgcn_exp2f(p4[t][4 * g + 1] - m_run);
        float e2 = __builtin_amdgcn_exp2f(p4[t][4 * g + 2] - m_run);
        float e3 = __builtin_amdgcn_exp2f(p4[t][4 * g + 3] - m_run);
        rs += (e0 + e1) + (e2 + e3);
        w[t][g][0] = pack_bf2(e0, e1);
        w[t][g][1] = pack_bf2(e2, e3);
      }
    rs += __shfl_xor(rs, 32);
    l_run += rs;

    // redistribute packed P into PV A-frags via permlane32_swap
    bf16x8 pa[4];
#pragma unroll
    for (int ks = 0; ks < 4; ++ks) {
      const int t = ks >> 1, q2 = (ks & 1) * 2;
      auto s0 = __builtin_amdgcn_permlane32_swap(w[t][q2][0], w[t][q2 + 1][0], false, false);
      auto s1 = __builtin_amdgcn_permlane32_swap(w[t][q2][1], w[t][q2 + 1][1], false, false);
      union { u32 u[4]; bf16x8 v; } cv;
      cv.u[0] = s0[0]; cv.u[1] = s1[0]; cv.u[2] = s0[1]; cv.u[3] = s1[1];
      pa[ks] = cv.v;
    }

    __builtin_amdgcn_s_setprio(1);
#pragma unroll
    for (int ks = 0; ks < 4; ++ks) {
      oacc[0] = __builtin_amdgcn_mfma_f32_32x32x16_bf16(pa[ks], vb[0][ks], oacc[0], 0, 0, 0);
      oacc[1] = __builtin_amdgcn_mfma_f32_32x32x16_bf16(pa[ks], vb[1][ks], oacc[1], 0, 0, 0);
    }
    __builtin_amdgcn_s_setprio(0);
  };

  stage(0, 0);
  for (int kt = 0; kt < 32; kt += 2) {
    // half A: prefetch kt+1 -> buf1, compute kt from buf0
    stage((kt + 1) * 64, 1);
    asm volatile("s_waitcnt vmcnt(4)" ::: "memory");
    __builtin_amdgcn_s_barrier();
    asm volatile("" ::: "memory");
    compute(Ks[0], Vs[0]);
    asm volatile("" ::: "memory");
    __builtin_amdgcn_s_barrier();
    // half B: prefetch kt+2 -> buf0, compute kt+1 from buf1
    if (kt + 2 < 32) {
      stage((kt + 2) * 64, 0);
      asm volatile("s_waitcnt vmcnt(4)" ::: "memory");
    } else {
      asm volatile("s_waitcnt vmcnt(0)" ::: "memory");
    }
    __builtin_amdgcn_s_barrier();
    asm volatile("" ::: "memory");
    compute(Ks[1], Vs[1]);
    asm volatile("" ::: "memory");
    __builtin_amdgcn_s_barrier();
  }

  // epilogue: O rows = qrow(reg), cols = dt*32 + l31
  float linv = __builtin_amdgcn_rcpf(l_run);
  const size_t orow0 = bq + q0 + wave * 32;
#pragma unroll
  for (int r = 0; r < 16; ++r) {
    int qr = (r & 3) + 8 * (r >> 2) + 4 * hi;
    float li = __shfl(linv, qr);
    size_t rb = (orow0 + qr) * 1024 + hc + l31;
    Oa[rb]      = f2bf(oacc[0][r] * li);
    Oa[rb + 32] = f2bf(oacc[1][r] * li);
  }
}

// ---------------- GEMM2: out[8192][1024] = Oa @ Wout^T + b_out (fp32) ----------------
__global__ __launch_bounds__(256, 3)
void k_gemm_out(const u16* __restrict__ Ob, const u16* __restrict__ Wb,
                const float* __restrict__ bout, float* __restrict__ out) {
  __shared__ u16 As[128 * 32], Bs[128 * 32];
  const int tid = threadIdx.x, lane = tid & 63, wave = tid >> 6;
  const int lr = lane & 15, lg = lane >> 4;
  const int wr = wave >> 1, wc = wave & 1;
  // bijective XCD swizzle over 512 workgroups
  const int wg = blockIdx.x + 8 * blockIdx.y;
  const int swz = (wg & 7) * 64 + (wg >> 3);
  const int m0 = (swz >> 3) * 128, n0 = (swz & 7) * 128;
  f32x4 acc[4][4] = {};

  for (int k0 = 0; k0 < 1024; k0 += 32) {
#pragma unroll
    for (int i = 0; i < 2; ++i) {
      int gc = ((tid & 3) ^ ((tid >> 2) & 3)) << 3;
      GLDS16(Ob + (size_t)(m0 + i * 64 + (tid >> 2)) * 1024 + k0 + gc, As + i * 2048 + wave * 512);
      GLDS16(Wb + (size_t)(n0 + i * 64 + (tid >> 2)) * 1024 + k0 + gc, Bs + i * 2048 + wave * 512);
    }
    __syncthreads();
    bf16x8 af[4], bfr[4];
#pragma unroll
    for (int t = 0; t < 4; ++t) {
      int ch = ((lg ^ (lr & 3)) & 3) << 3;
      af[t]  = *reinterpret_cast<const bf16x8*>(As + (wr * 64 + t * 16 + lr) * 32 + ch);
      bfr[t] = *reinterpret_cast<const bf16x8*>(Bs + (wc * 64 + t * 16 + lr) * 32 + ch);
    }
#pragma unroll
    for (int mi = 0; mi < 4; ++mi)
#pragma unroll
      for (int ni = 0; ni < 4; ++ni)
        acc[mi][ni] = __builtin_amdgcn_mfma_f32_16x16x32_bf16(af[mi], bfr[ni], acc[mi][ni], 0, 0, 0);
    __syncthreads();
  }

#pragma unroll
  for (int mi = 0; mi < 4; ++mi) {
    int row = m0 + wr * 64 + mi * 16 + (lg << 2);
#pragma unroll
    for (int ni = 0; ni < 4; ++ni) {
      int col = n0 + wc * 64 + ni * 16 + lr;
      float bias = bout[col];
#pragma unroll
      for (int j = 0; j < 4; ++j)
        out[(size_t)(row + j) * 1024 + col] = acc[mi][ni][j] + bias;
    }
  }
}

extern "C" void kernel_launch(void* const* d_in, const int* in_sizes, int n_in,
                              void* d_out, int out_size, void* d_ws, size_t ws_size,
                              hipStream_t stream) {
  const float* x     = (const float*)d_in[0];
  const float* Wqkv  = (const float*)d_in[1];
  const float* Wlora = (const float*)d_in[2];
  const float* blora = (const float*)d_in[3];
  const float* Aq    = (const float*)d_in[4];
  const float* Bq    = (const float*)d_in[5];
  const float* Av    = (const float*)d_in[6];
  const float* Bv    = (const float*)d_in[7];
  const float* Wout  = (const float*)d_in[8];
  const float* bout  = (const float*)d_in[9];
  float* out = (float*)d_out;

  char* w = (char*)d_ws;
  auto alloc = [&](size_t bytes) { char* p = w; w += (bytes + 255) & ~(size_t)255; return p; };
  u16*   Xb    = (u16*)alloc((size_t)8192 * 1024 * 2);   // x bf16  (reused as Oa later)
  u16*   Weff  = (u16*)alloc((size_t)3072 * 1024 * 2);
  float* beff  = (float*)alloc((size_t)3072 * 4);
  u16*   Woutb = (u16*)alloc((size_t)1024 * 1024 * 2);
  u16*   Y     = (u16*)alloc((size_t)8192 * 3072 * 2);   // qkv (q pre-scaled by log2e/8)
  u16*   Vt    = (u16*)alloc((size_t)4096 * 1024 * 2 * 2); // [(b*16+h)*64+d][2048] bf16
  u16*   Oa    = Xb;  // alias: Xb is dead after GEMM1

  k_prep<<<dim3(21504), dim3(256), 0, stream>>>(x, Wqkv, Wlora, blora, Aq, Bq, Av, Bv, Wout,
                                                Xb, Weff, beff, Woutb);
  k_gemm_qkv<<<dim3(24, 64), dim3(256), 0, stream>>>(Xb, Weff, beff, Y);
  k_vtrans<<<dim3(32, 64), dim3(256), 0, stream>>>(Y, Vt);
  k_attn<<<dim3(16, 64), dim3(256), 0, stream>>>(Y, Vt, Oa);
  k_gemm_out<<<dim3(8, 64), dim3(256), 0, stream>>>(Oa, Woutb, bout, out);
}

// Round 8
// 336.571 us; speedup vs baseline: 1.2994x; 1.2994x over previous
//
#include <hip/hip_runtime.h>
#include <hip/hip_bf16.h>

typedef unsigned short u16;
typedef unsigned int u32;
typedef __attribute__((ext_vector_type(8))) short bf16x8;   // 8 bf16 in 4 VGPRs
typedef __attribute__((ext_vector_type(4))) float f32x4;
typedef __attribute__((ext_vector_type(16))) float f32x16;

#define GLDS16(gptr, lptr)                                                        \
  __builtin_amdgcn_global_load_lds(                                               \
      (__attribute__((address_space(1))) const void*)(gptr),                      \
      (__attribute__((address_space(3))) void*)(lptr), 16, 0, 0)

__device__ __forceinline__ u16 f2bf(float f) {
  union { float f; unsigned u; } v; v.f = f;
  unsigned r = v.u + 0x7fffu + ((v.u >> 16) & 1u);   // RNE, finite inputs only
  return (u16)(r >> 16);
}

__device__ __forceinline__ u32 pack_bf2(float a, float b) {
  union { __hip_bfloat162 h2; u32 u; } v;
  v.h2 = __float22bfloat162_rn(make_float2(a, b));
  return v.u;
}

// ---------------- fused prep: x-cast | Wout-cast | W_eff/b_eff ----------------
__global__ void k_prep(const float* __restrict__ x, const float* __restrict__ Wqkv,
                       const float* __restrict__ Wlora, const float* __restrict__ blora,
                       const float* __restrict__ Aq, const float* __restrict__ Bq,
                       const float* __restrict__ Av, const float* __restrict__ Bv,
                       const float* __restrict__ Wout,
                       u16* __restrict__ Xb, u16* __restrict__ Weff,
                       float* __restrict__ beff, u16* __restrict__ Woutb) {
  const int bid = blockIdx.x, tid = threadIdx.x;
  if (bid < 8192) {                       // x: 8192*1024 f32 -> bf16, float4-wide
    int i = bid * 256 + tid;
    float4 f = reinterpret_cast<const float4*>(x)[i];
    ushort4 u;
    u.x = f2bf(f.x); u.y = f2bf(f.y); u.z = f2bf(f.z); u.w = f2bf(f.w);
    reinterpret_cast<ushort4*>(Xb)[i] = u;
  } else if (bid < 9216) {                // Wout: 1024*1024
    int i = (bid - 8192) * 256 + tid;
    float4 f = reinterpret_cast<const float4*>(Wout)[i];
    ushort4 u;
    u.x = f2bf(f.x); u.y = f2bf(f.y); u.z = f2bf(f.z); u.w = f2bf(f.w);
    reinterpret_cast<ushort4*>(Woutb)[i] = u;
  } else {                                // W_eff
    int idx = (bid - 9216) * 256 + tid;   // < 3072*1024
    int o = idx >> 10, c = idx & 1023;
    float w = Wqkv[idx];
    if (o < 1024) {
      float lr = 0.f;
#pragma unroll
      for (int r = 0; r < 8; ++r) lr += Bq[o * 8 + r] * Aq[r * 1024 + c];
      w += Wlora[idx] + 0.125f * lr;
    } else if (o >= 2048) {
      int o2 = o - 2048;
      float lr = 0.f;
#pragma unroll
      for (int r = 0; r < 8; ++r) lr += Bv[o2 * 8 + r] * Av[r * 1024 + c];
      w += Wlora[idx] + 0.125f * lr;
    }
    Weff[idx] = f2bf(w);
    if (c == 0) beff[o] = (o < 1024 || o >= 2048) ? blora[o] : 0.f;
  }
}

// ---------------- GEMM1: Y[8192][3072] = Xb @ Weff^T + beff ----------------
// 256x256 tile, BK=64, 8 waves (2x4), 128KB dbuf LDS, counted-vmcnt pipeline.
// q slice scaled by log2(e)/8 (softmax scale folded, exp2-domain for k_attn).
__global__ __launch_bounds__(512, 2)
void k_gemm_qkv(const u16* __restrict__ Xb, const u16* __restrict__ Weff,
                const float* __restrict__ beff, u16* __restrict__ Y) {
  __shared__ u16 As[2 * 256 * 64], Bs[2 * 256 * 64];   // 64KB + 64KB
  const int tid = threadIdx.x, lane = tid & 63, wave = tid >> 6;
  const int lr = lane & 15, lg = (lane >> 4) & 3;
  const int wr = wave >> 2, wc = wave & 3;             // 2 x 4 wave grid
  const int wg = blockIdx.x + 12 * blockIdx.y;
  const int swz = (wg & 7) * 48 + (wg >> 3);           // bijective: 384 % 8 == 0
  const int m0 = (swz / 12) * 256, n0 = (swz % 12) * 256;

  const int srow = wave * 8 + (lane >> 3);             // stage row within a 64-row pass
  const int schunk = lane & 7;
  f32x4 acc[8][4] = {};

  auto stage = [&](int kt, int bb) {
    const int k0 = kt * 64;
    const int lb = bb * 16384 + (wave * 8) * 64;       // wave-uniform LDS dest base (u16)
#pragma unroll
    for (int i = 0; i < 4; ++i) {
      int row = i * 64 + srow;
      int gc = (schunk ^ (row & 7)) << 3;              // pre-swizzled global source chunk
      GLDS16(Xb   + (size_t)(m0 + row) * 1024 + k0 + gc, &As[lb + i * 4096]);
      GLDS16(Weff + (size_t)(n0 + row) * 1024 + k0 + gc, &Bs[lb + i * 4096]);
    }
  };

  stage(0, 0);
  stage(1, 1);
  asm volatile("s_waitcnt vmcnt(8)" ::: "memory");     // tile 0 landed; tile 1 in flight
  __builtin_amdgcn_s_barrier();

  for (int kt = 0; kt < 16; ++kt) {
    const int cur = kt & 1;
    const int abase = cur * 16384, bbase = cur * 16384;
#pragma unroll
    for (int mh = 0; mh < 2; ++mh) {
      bf16x8 af[4][2];
#pragma unroll
      for (int mi = 0; mi < 4; ++mi)
#pragma unroll
        for (int kk = 0; kk < 2; ++kk)
          af[mi][kk] = *reinterpret_cast<const bf16x8*>(
              &As[abase + (wr * 128 + (mh * 4 + mi) * 16 + lr) * 64 + (((kk * 4 + lg) ^ (lr & 7)) << 3)]);
#pragma unroll
      for (int nh = 0; nh < 2; ++nh) {
        bf16x8 bf[2][2];
#pragma unroll
        for (int ni = 0; ni < 2; ++ni)
#pragma unroll
          for (int kk = 0; kk < 2; ++kk)
            bf[ni][kk] = *reinterpret_cast<const bf16x8*>(
                &Bs[bbase + (wc * 64 + (nh * 2 + ni) * 16 + lr) * 64 + (((kk * 4 + lg) ^ (lr & 7)) << 3)]);
        __builtin_amdgcn_s_setprio(1);
#pragma unroll
        for (int mi = 0; mi < 4; ++mi)
#pragma unroll
          for (int ni = 0; ni < 2; ++ni)
#pragma unroll
            for (int kk = 0; kk < 2; ++kk)
              acc[mh * 4 + mi][nh * 2 + ni] = __builtin_amdgcn_mfma_f32_16x16x32_bf16(
                  af[mi][kk], bf[ni][kk], acc[mh * 4 + mi][nh * 2 + ni], 0, 0, 0);
        __builtin_amdgcn_s_setprio(0);
        __builtin_amdgcn_sched_barrier(0);             // pin quadrant order (reg pressure)
      }
    }
    if (kt == 15) break;
    __builtin_amdgcn_s_barrier();                      // all waves done reading buf[cur]
    if (kt + 2 < 16) {
      stage(kt + 2, cur);                              // refill the buffer just retired
      asm volatile("s_waitcnt vmcnt(8)" ::: "memory"); // tile kt+1 landed; kt+2 in flight
    } else {
      asm volatile("s_waitcnt vmcnt(0)" ::: "memory");
    }
    __builtin_amdgcn_s_barrier();
  }

#pragma unroll
  for (int mi = 0; mi < 8; ++mi) {
    int row = m0 + wr * 128 + mi * 16 + (lg << 2);
#pragma unroll
    for (int ni = 0; ni < 4; ++ni) {
      int col = n0 + wc * 64 + ni * 16 + lr;
      float bias = beff[col];
      bool isq = col < 1024;
#pragma unroll
      for (int j = 0; j < 4; ++j) {
        float v = acc[mi][ni][j] + bias;
        if (isq) v *= 0.18033688011112042f;  // log2(e)/8: softmax scale + exp2 domain
        Y[(size_t)(row + j) * 3072 + col] = f2bf(v);
      }
    }
  }
}

// ---------------- Vt transpose: Vt[(b*16+h)*64+d][n] = Y[b*2048+n][2048+h*64+d] ----------------
__global__ __launch_bounds__(256)
void k_vtrans(const u16* __restrict__ Y, u16* __restrict__ Vt) {
  __shared__ u16 Ls[64 * 65];
  const int t = threadIdx.x;
  const int bh = blockIdx.y, b = bh >> 4, h = bh & 15;
  const int n0 = blockIdx.x * 64;
#pragma unroll
  for (int c = 0; c < 2; ++c) {
    int idx = c * 256 + t;
    int nl = idx >> 3, d0 = (idx & 7) * 8;
    bf16x8 val = *reinterpret_cast<const bf16x8*>(
        Y + (size_t)(b * 2048 + n0 + nl) * 3072 + 2048 + h * 64 + d0);
#pragma unroll
    for (int j = 0; j < 8; ++j) Ls[(d0 + j) * 65 + nl] = (u16)val[j];
  }
  __syncthreads();
#pragma unroll
  for (int c = 0; c < 2; ++c) {
    int idx = c * 256 + t;
    int dl = idx >> 3, nn = (idx & 7) * 8;
    bf16x8 outv;
#pragma unroll
    for (int j = 0; j < 8; ++j) outv[j] = (short)Ls[dl * 65 + nn + j];
    *reinterpret_cast<bf16x8*>(Vt + (size_t)(bh * 64 + dl) * 2048 + n0 + nn) = outv;
  }
}

// ---------------- flash attention: 32x32 swapped QK^T, P in-register (round-6 known-good) ----------------
__global__ __launch_bounds__(256, 3)
void k_attn(const u16* __restrict__ Y, const u16* __restrict__ Vt, u16* __restrict__ Oa) {
  __shared__ u16 Ks[2][64 * 64], Vs[2][64 * 64];
  const int tid = threadIdx.x, lane = tid & 63, wave = tid >> 6;
  const int b = blockIdx.y >> 4, h = blockIdx.y & 15;
  const int q0 = blockIdx.x * 128;
  const int l31 = lane & 31, hi = lane >> 5;
  const size_t bq = (size_t)b * 2048;
  const size_t bv = (size_t)b * 1024 + h * 64;
  const int hc = h * 64;

  bf16x8 qb[4];
  {
    const u16* yr = Y + (bq + q0 + wave * 32 + l31) * 3072 + hc + hi * 8;
#pragma unroll
    for (int ks = 0; ks < 4; ++ks)
      qb[ks] = *reinterpret_cast<const bf16x8*>(yr + ks * 16);
  }

  float m_run = -1e30f, l_run = 0.f;
  f32x16 oacc[2] = {};

  const int sr = tid >> 3, sc = tid & 7;
  auto stage = [&](int key0, int bb) {
#pragma unroll
    for (int i = 0; i < 2; ++i) {
      int r = i * 32 + sr;
      int gc = (sc ^ (r & 7)) << 3;
      GLDS16(Y + (bq + key0 + r) * 3072 + 1024 + hc + gc, &Ks[bb][i * 2048 + wave * 512]);
      GLDS16(Vt + (bv + r) * 2048 + key0 + gc,            &Vs[bb][i * 2048 + wave * 512]);
    }
  };

  stage(0, 0);
  for (int kt = 0; kt < 32; ++kt) {
    const int cur = kt & 1;
    if (kt < 31) {
      stage((kt + 1) * 64, cur ^ 1);
      asm volatile("s_waitcnt vmcnt(4)" ::: "memory");
    } else {
      asm volatile("s_waitcnt vmcnt(0)" ::: "memory");
    }
    __builtin_amdgcn_s_barrier();
    asm volatile("" ::: "memory");

    bf16x8 kb[2][4], vb[2][4];
#pragma unroll
    for (int t = 0; t < 2; ++t) {
      const u16* kbase = &Ks[cur][(t * 32 + l31) * 64];
      int rx = (t * 32 + l31) & 7;
#pragma unroll
      for (int ks = 0; ks < 4; ++ks)
        kb[t][ks] = *reinterpret_cast<const bf16x8*>(kbase + (((ks * 2 + hi) ^ rx) << 3));
    }
#pragma unroll
    for (int dt = 0; dt < 2; ++dt) {
      const u16* vbase = &Vs[cur][(dt * 32 + l31) * 64];
      int rx = (dt * 32 + l31) & 7;
#pragma unroll
      for (int ks = 0; ks < 4; ++ks)
        vb[dt][ks] = *reinterpret_cast<const bf16x8*>(vbase + (((ks * 2 + hi) ^ rx) << 3));
    }

    f32x16 p4[2] = {};
    __builtin_amdgcn_s_setprio(1);
#pragma unroll
    for (int t = 0; t < 2; ++t)
#pragma unroll
      for (int ks = 0; ks < 4; ++ks)
        p4[t] = __builtin_amdgcn_mfma_f32_32x32x16_bf16(kb[t][ks], qb[ks], p4[t], 0, 0, 0);
    __builtin_amdgcn_s_setprio(0);

    float mx[8];
#pragma unroll
    for (int r = 0; r < 8; ++r)
      mx[r] = fmaxf(fmaxf(p4[0][r], p4[0][r + 8]), fmaxf(p4[1][r], p4[1][r + 8]));
#pragma unroll
    for (int s = 4; s > 0; s >>= 1)
#pragma unroll
      for (int r = 0; r < s; ++r) mx[r] = fmaxf(mx[r], mx[r + s]);
    float tmax = fmaxf(mx[0], __shfl_xor(mx[0], 32));

    if (__any(tmax > m_run + 11.0f)) {
      float mnew = fmaxf(m_run, tmax);
      float alpha = __builtin_amdgcn_exp2f(m_run - mnew);
      m_run = mnew;
      l_run *= alpha;
#pragma unroll
      for (int r = 0; r < 16; ++r) {
        float ab = __shfl(alpha, (r & 3) + 8 * (r >> 2) + 4 * hi);
        oacc[0][r] *= ab;
        oacc[1][r] *= ab;
      }
    }

    float rs = 0.f;
    u32 w[2][4][2];
#pragma unroll
    for (int t = 0; t < 2; ++t)
#pragma unroll
      for (int g = 0; g < 4; ++g) {
        float e0 = __builtin_amdgcn_exp2f(p4[t][4 * g + 0] - m_run);
        float e1 = __builtin_amdgcn_exp2f(p4[t][4 * g + 1] - m_run);
        float e2 = __builtin_amdgcn_exp2f(p4[t][4 * g + 2] - m_run);
        float e3 = __builtin_amdgcn_exp2f(p4[t][4 * g + 3] - m_run);
        rs += (e0 + e1) + (e2 + e3);
        w[t][g][0] = pack_bf2(e0, e1);
        w[t][g][1] = pack_bf2(e2, e3);
      }
    rs += __shfl_xor(rs, 32);
    l_run += rs;

    bf16x8 pa[4];
#pragma unroll
    for (int ks = 0; ks < 4; ++ks) {
      const int t = ks >> 1, q2 = (ks & 1) * 2;
      auto s0 = __builtin_amdgcn_permlane32_swap(w[t][q2][0], w[t][q2 + 1][0], false, false);
      auto s1 = __builtin_amdgcn_permlane32_swap(w[t][q2][1], w[t][q2 + 1][1], false, false);
      union { u32 u[4]; bf16x8 v; } cv;
      cv.u[0] = s0[0]; cv.u[1] = s1[0]; cv.u[2] = s0[1]; cv.u[3] = s1[1];
      pa[ks] = cv.v;
    }

    __builtin_amdgcn_s_setprio(1);
#pragma unroll
    for (int ks = 0; ks < 4; ++ks) {
      oacc[0] = __builtin_amdgcn_mfma_f32_32x32x16_bf16(pa[ks], vb[0][ks], oacc[0], 0, 0, 0);
      oacc[1] = __builtin_amdgcn_mfma_f32_32x32x16_bf16(pa[ks], vb[1][ks], oacc[1], 0, 0, 0);
    }
    __builtin_amdgcn_s_setprio(0);

    asm volatile("" ::: "memory");
    __builtin_amdgcn_s_barrier();
  }

  float linv = __builtin_amdgcn_rcpf(l_run);
  const size_t orow0 = bq + q0 + wave * 32;
#pragma unroll
  for (int r = 0; r < 16; ++r) {
    int qr = (r & 3) + 8 * (r >> 2) + 4 * hi;
    float li = __shfl(linv, qr);
    size_t rb = (orow0 + qr) * 1024 + hc + l31;
    Oa[rb]      = f2bf(oacc[0][r] * li);
    Oa[rb + 32] = f2bf(oacc[1][r] * li);
  }
}

// ---------------- GEMM2: out[8192][1024] = Oa @ Wout^T + b_out (fp32) ----------------
__global__ __launch_bounds__(256, 3)
void k_gemm_out(const u16* __restrict__ Ob, const u16* __restrict__ Wb,
                const float* __restrict__ bout, float* __restrict__ out) {
  __shared__ u16 As[128 * 32], Bs[128 * 32];
  const int tid = threadIdx.x, lane = tid & 63, wave = tid >> 6;
  const int lr = lane & 15, lg = lane >> 4;
  const int wr = wave >> 1, wc = wave & 1;
  const int wg = blockIdx.x + 8 * blockIdx.y;
  const int swz = (wg & 7) * 64 + (wg >> 3);
  const int m0 = (swz >> 3) * 128, n0 = (swz & 7) * 128;
  f32x4 acc[4][4] = {};

  for (int k0 = 0; k0 < 1024; k0 += 32) {
#pragma unroll
    for (int i = 0; i < 2; ++i) {
      int gc = ((tid & 3) ^ ((tid >> 2) & 3)) << 3;
      GLDS16(Ob + (size_t)(m0 + i * 64 + (tid >> 2)) * 1024 + k0 + gc, As + i * 2048 + wave * 512);
      GLDS16(Wb + (size_t)(n0 + i * 64 + (tid >> 2)) * 1024 + k0 + gc, Bs + i * 2048 + wave * 512);
    }
    __syncthreads();
    bf16x8 af[4], bfr[4];
#pragma unroll
    for (int t = 0; t < 4; ++t) {
      int ch = ((lg ^ (lr & 3)) & 3) << 3;
      af[t]  = *reinterpret_cast<const bf16x8*>(As + (wr * 64 + t * 16 + lr) * 32 + ch);
      bfr[t] = *reinterpret_cast<const bf16x8*>(Bs + (wc * 64 + t * 16 + lr) * 32 + ch);
    }
#pragma unroll
    for (int mi = 0; mi < 4; ++mi)
#pragma unroll
      for (int ni = 0; ni < 4; ++ni)
        acc[mi][ni] = __builtin_amdgcn_mfma_f32_16x16x32_bf16(af[mi], bfr[ni], acc[mi][ni], 0, 0, 0);
    __syncthreads();
  }

#pragma unroll
  for (int mi = 0; mi < 4; ++mi) {
    int row = m0 + wr * 64 + mi * 16 + (lg << 2);
#pragma unroll
    for (int ni = 0; ni < 4; ++ni) {
      int col = n0 + wc * 64 + ni * 16 + lr;
      float bias = bout[col];
#pragma unroll
      for (int j = 0; j < 4; ++j)
        out[(size_t)(row + j) * 1024 + col] = acc[mi][ni][j] + bias;
    }
  }
}

extern "C" void kernel_launch(void* const* d_in, const int* in_sizes, int n_in,
                              void* d_out, int out_size, void* d_ws, size_t ws_size,
                              hipStream_t stream) {
  const float* x     = (const float*)d_in[0];
  const float* Wqkv  = (const float*)d_in[1];
  const float* Wlora = (const float*)d_in[2];
  const float* blora = (const float*)d_in[3];
  const float* Aq    = (const float*)d_in[4];
  const float* Bq    = (const float*)d_in[5];
  const float* Av    = (const float*)d_in[6];
  const float* Bv    = (const float*)d_in[7];
  const float* Wout  = (const float*)d_in[8];
  const float* bout  = (const float*)d_in[9];
  float* out = (float*)d_out;

  char* w = (char*)d_ws;
  auto alloc = [&](size_t bytes) { char* p = w; w += (bytes + 255) & ~(size_t)255; return p; };
  u16*   Xb    = (u16*)alloc((size_t)8192 * 1024 * 2);   // x bf16  (reused as Oa later)
  u16*   Weff  = (u16*)alloc((size_t)3072 * 1024 * 2);
  float* beff  = (float*)alloc((size_t)3072 * 4);
  u16*   Woutb = (u16*)alloc((size_t)1024 * 1024 * 2);
  u16*   Y     = (u16*)alloc((size_t)8192 * 3072 * 2);   // qkv (q pre-scaled by log2e/8)
  u16*   Vt    = (u16*)alloc((size_t)4096 * 1024 * 2 * 2); // [(b*16+h)*64+d][2048] bf16
  u16*   Oa    = Xb;  // alias: Xb is dead after GEMM1

  k_prep<<<dim3(21504), dim3(256), 0, stream>>>(x, Wqkv, Wlora, blora, Aq, Bq, Av, Bv, Wout,
                                                Xb, Weff, beff, Woutb);
  k_gemm_qkv<<<dim3(12, 32), dim3(512), 0, stream>>>(Xb, Weff, beff, Y);
  k_vtrans<<<dim3(32, 64), dim3(256), 0, stream>>>(Y, Vt);
  k_attn<<<dim3(16, 64), dim3(256), 0, stream>>>(Y, Vt, Oa);
  k_gemm_out<<<dim3(8, 64), dim3(256), 0, stream>>>(Oa, Woutb, bout, out);
}

// Round 9
// 314.074 us; speedup vs baseline: 1.3925x; 1.0716x over previous
//
#include <hip/hip_runtime.h>
#include <hip/hip_bf16.h>

typedef unsigned short u16;
typedef unsigned int u32;
typedef __attribute__((ext_vector_type(8))) short bf16x8;   // 8 bf16 in 4 VGPRs
typedef __attribute__((ext_vector_type(4))) float f32x4;
typedef __attribute__((ext_vector_type(16))) float f32x16;

#define GLDS16(gptr, lptr)                                                        \
  __builtin_amdgcn_global_load_lds(                                               \
      (__attribute__((address_space(1))) const void*)(gptr),                      \
      (__attribute__((address_space(3))) void*)(lptr), 16, 0, 0)

__device__ __forceinline__ u16 f2bf(float f) {
  union { float f; unsigned u; } v; v.f = f;
  unsigned r = v.u + 0x7fffu + ((v.u >> 16) & 1u);   // RNE, finite inputs only
  return (u16)(r >> 16);
}

__device__ __forceinline__ u32 pack_bf2(float a, float b) {
  union { __hip_bfloat162 h2; u32 u; } v;
  v.h2 = __float22bfloat162_rn(make_float2(a, b));
  return v.u;
}

// ---------------- fused prep: x-cast | Wout-cast | W_eff/b_eff ----------------
__global__ void k_prep(const float* __restrict__ x, const float* __restrict__ Wqkv,
                       const float* __restrict__ Wlora, const float* __restrict__ blora,
                       const float* __restrict__ Aq, const float* __restrict__ Bq,
                       const float* __restrict__ Av, const float* __restrict__ Bv,
                       const float* __restrict__ Wout,
                       u16* __restrict__ Xb, u16* __restrict__ Weff,
                       float* __restrict__ beff, u16* __restrict__ Woutb) {
  const int bid = blockIdx.x, tid = threadIdx.x;
  if (bid < 8192) {                       // x: 8192*1024 f32 -> bf16, float4-wide
    int i = bid * 256 + tid;
    float4 f = reinterpret_cast<const float4*>(x)[i];
    ushort4 u;
    u.x = f2bf(f.x); u.y = f2bf(f.y); u.z = f2bf(f.z); u.w = f2bf(f.w);
    reinterpret_cast<ushort4*>(Xb)[i] = u;
  } else if (bid < 9216) {                // Wout: 1024*1024
    int i = (bid - 8192) * 256 + tid;
    float4 f = reinterpret_cast<const float4*>(Wout)[i];
    ushort4 u;
    u.x = f2bf(f.x); u.y = f2bf(f.y); u.z = f2bf(f.z); u.w = f2bf(f.w);
    reinterpret_cast<ushort4*>(Woutb)[i] = u;
  } else {                                // W_eff
    int idx = (bid - 9216) * 256 + tid;   // < 3072*1024
    int o = idx >> 10, c = idx & 1023;
    float w = Wqkv[idx];
    if (o < 1024) {
      float lr = 0.f;
#pragma unroll
      for (int r = 0; r < 8; ++r) lr += Bq[o * 8 + r] * Aq[r * 1024 + c];
      w += Wlora[idx] + 0.125f * lr;
    } else if (o >= 2048) {
      int o2 = o - 2048;
      float lr = 0.f;
#pragma unroll
      for (int r = 0; r < 8; ++r) lr += Bv[o2 * 8 + r] * Av[r * 1024 + c];
      w += Wlora[idx] + 0.125f * lr;
    }
    Weff[idx] = f2bf(w);
    if (c == 0) beff[o] = (o < 1024 || o >= 2048) ? blora[o] : 0.f;
  }
}

// ---------------- GEMM1: Y/Vt = Xb @ Weff^T + beff ----------------
// 256x128 tile, BK=64, 8 waves (4x2), 96KB dbuf LDS, counted vmcnt(6).
// Grid 768 = 3 x 256 CUs exactly. q slice scaled by log2(e)/8.
// V-tiles (n0>=2048): bias + LDS transpose + coalesced Vt store (k_vtrans fused).
__global__ __launch_bounds__(512, 2)
void k_gemm_qkv(const u16* __restrict__ Xb, const u16* __restrict__ Weff,
                const float* __restrict__ beff, u16* __restrict__ Y, u16* __restrict__ Vt) {
  __shared__ u16 SH[49152];                         // 96KB: A dbuf 2x16384, B dbuf 2x8192 (u16)
  const int tid = threadIdx.x, lane = tid & 63, wave = tid >> 6;
  const int lr = lane & 15, lg = (lane >> 4) & 3;
  const int wr = wave >> 1, wc = wave & 1;          // 4x2 wave grid
  const int wg = blockIdx.x;
  const int swz = (wg & 7) * 96 + (wg >> 3);        // bijective: 768 % 8 == 0
  const int m0 = (swz / 24) * 256, n0 = (swz % 24) * 128;

  auto stage = [&](int kt, int bb) {
    const int k0 = kt * 64;
    const int r8 = tid >> 3, ch = tid & 7;
#pragma unroll
    for (int i = 0; i < 4; ++i) {                   // A: 256 rows
      int row = i * 64 + r8;
      int gc = (ch ^ (row & 7)) << 3;
      GLDS16(Xb + (size_t)(m0 + row) * 1024 + k0 + gc, &SH[bb * 16384 + (i * 64 + wave * 8) * 64]);
    }
#pragma unroll
    for (int i = 0; i < 2; ++i) {                   // B: 128 rows
      int row = i * 64 + r8;
      int gc = (ch ^ (row & 7)) << 3;
      GLDS16(Weff + (size_t)(n0 + row) * 1024 + k0 + gc,
             &SH[32768 + bb * 8192 + (i * 64 + wave * 8) * 64]);
    }
  };

  f32x4 acc[4][4] = {};
  stage(0, 0);
  stage(1, 1);
  asm volatile("s_waitcnt vmcnt(6)" ::: "memory");  // tile 0 landed; tile 1 in flight
  __builtin_amdgcn_s_barrier();

  for (int kt = 0; kt < 16; ++kt) {
    const int cur = kt & 1;
    const u16* Ab = &SH[cur * 16384];
    const u16* Bb = &SH[32768 + cur * 8192];
    bf16x8 afr[4][2], bfr[4][2];
#pragma unroll
    for (int mi = 0; mi < 4; ++mi)
#pragma unroll
      for (int kk = 0; kk < 2; ++kk)
        afr[mi][kk] = *reinterpret_cast<const bf16x8*>(
            &Ab[(wr * 64 + mi * 16 + lr) * 64 + (((kk * 4 + lg) ^ (lr & 7)) << 3)]);
#pragma unroll
    for (int ni = 0; ni < 4; ++ni)
#pragma unroll
      for (int kk = 0; kk < 2; ++kk)
        bfr[ni][kk] = *reinterpret_cast<const bf16x8*>(
            &Bb[(wc * 64 + ni * 16 + lr) * 64 + (((kk * 4 + lg) ^ (lr & 7)) << 3)]);
    __builtin_amdgcn_s_setprio(1);
#pragma unroll
    for (int mi = 0; mi < 4; ++mi)
#pragma unroll
      for (int ni = 0; ni < 4; ++ni)
#pragma unroll
        for (int kk = 0; kk < 2; ++kk)
          acc[mi][ni] = __builtin_amdgcn_mfma_f32_16x16x32_bf16(
              afr[mi][kk], bfr[ni][kk], acc[mi][ni], 0, 0, 0);
    __builtin_amdgcn_s_setprio(0);
    if (kt == 15) break;
    __builtin_amdgcn_s_barrier();                   // all waves done reading buf[cur]
    if (kt + 2 < 16) {
      stage(kt + 2, cur);
      asm volatile("s_waitcnt vmcnt(6)" ::: "memory");
    } else {
      asm volatile("s_waitcnt vmcnt(0)" ::: "memory");
    }
    __builtin_amdgcn_s_barrier();
  }

  if (n0 < 2048) {                                  // q/k tiles -> Y
#pragma unroll
    for (int mi = 0; mi < 4; ++mi) {
      int row = m0 + wr * 64 + mi * 16 + (lg << 2);
#pragma unroll
      for (int ni = 0; ni < 4; ++ni) {
        int col = n0 + wc * 64 + ni * 16 + lr;
        float bias = beff[col];
        bool isq = col < 1024;
#pragma unroll
        for (int j = 0; j < 4; ++j) {
          float v = acc[mi][ni][j] + bias;
          if (isq) v *= 0.18033688011112042f;       // log2(e)/8
          Y[(size_t)(row + j) * 3072 + col] = f2bf(v);
        }
      }
    }
  } else {                                          // V tiles -> Vt (fused transpose)
    __syncthreads();                                // SH free for reuse
    u32* L32 = reinterpret_cast<u32*>(SH);          // [hd_l:128][130 u32] (stride 260 u16)
#pragma unroll
    for (int mi = 0; mi < 4; ++mi) {
      int tok = wr * 64 + mi * 16 + (lg << 2);
#pragma unroll
      for (int ni = 0; ni < 4; ++ni) {
        int hd_l = wc * 64 + ni * 16 + lr;
        float bias = beff[n0 + hd_l];
        L32[hd_l * 130 + (tok >> 1)]     = pack_bf2(acc[mi][ni][0] + bias, acc[mi][ni][1] + bias);
        L32[hd_l * 130 + (tok >> 1) + 1] = pack_bf2(acc[mi][ni][2] + bias, acc[mi][ni][3] + bias);
      }
    }
    __syncthreads();
    const int b = m0 >> 11, tok0 = m0 & 2047;
    const int hdb = n0 - 2048;
#pragma unroll
    for (int p = 0; p < 8; ++p) {
      int idx = p * 512 + tid;                      // 4096 chunks of 8 u16
      int hd_l = idx >> 5, c = idx & 31;
      uint2 d0 = *reinterpret_cast<uint2*>(&L32[hd_l * 130 + c * 4]);
      uint2 d1 = *reinterpret_cast<uint2*>(&L32[hd_l * 130 + c * 4 + 2]);
      *reinterpret_cast<uint4*>(&Vt[((size_t)(b * 1024 + hdb + hd_l)) * 2048 + tok0 + c * 8]) =
          make_uint4(d0.x, d0.y, d1.x, d1.y);
    }
  }
}

// ---------------- flash attention: 32x32 swapped QK^T, P in-register (known-good) ----------------
__global__ __launch_bounds__(256, 3)
void k_attn(const u16* __restrict__ Y, const u16* __restrict__ Vt, u16* __restrict__ Oa) {
  __shared__ u16 Ks[2][64 * 64], Vs[2][64 * 64];
  const int tid = threadIdx.x, lane = tid & 63, wave = tid >> 6;
  const int b = blockIdx.y >> 4, h = blockIdx.y & 15;
  const int q0 = blockIdx.x * 128;
  const int l31 = lane & 31, hi = lane >> 5;
  const size_t bq = (size_t)b * 2048;
  const size_t bv = (size_t)b * 1024 + h * 64;
  const int hc = h * 64;

  bf16x8 qb[4];
  {
    const u16* yr = Y + (bq + q0 + wave * 32 + l31) * 3072 + hc + hi * 8;
#pragma unroll
    for (int ks = 0; ks < 4; ++ks)
      qb[ks] = *reinterpret_cast<const bf16x8*>(yr + ks * 16);
  }

  float m_run = -1e30f, l_run = 0.f;
  f32x16 oacc[2] = {};

  const int sr = tid >> 3, sc = tid & 7;
  auto stage = [&](int key0, int bb) {
#pragma unroll
    for (int i = 0; i < 2; ++i) {
      int r = i * 32 + sr;
      int gc = (sc ^ (r & 7)) << 3;
      GLDS16(Y + (bq + key0 + r) * 3072 + 1024 + hc + gc, &Ks[bb][i * 2048 + wave * 512]);
      GLDS16(Vt + (bv + r) * 2048 + key0 + gc,            &Vs[bb][i * 2048 + wave * 512]);
    }
  };

  stage(0, 0);
  for (int kt = 0; kt < 32; ++kt) {
    const int cur = kt & 1;
    if (kt < 31) {
      stage((kt + 1) * 64, cur ^ 1);
      asm volatile("s_waitcnt vmcnt(4)" ::: "memory");
    } else {
      asm volatile("s_waitcnt vmcnt(0)" ::: "memory");
    }
    __builtin_amdgcn_s_barrier();
    asm volatile("" ::: "memory");

    bf16x8 kb[2][4], vb[2][4];
#pragma unroll
    for (int t = 0; t < 2; ++t) {
      const u16* kbase = &Ks[cur][(t * 32 + l31) * 64];
      int rx = (t * 32 + l31) & 7;
#pragma unroll
      for (int ks = 0; ks < 4; ++ks)
        kb[t][ks] = *reinterpret_cast<const bf16x8*>(kbase + (((ks * 2 + hi) ^ rx) << 3));
    }
#pragma unroll
    for (int dt = 0; dt < 2; ++dt) {
      const u16* vbase = &Vs[cur][(dt * 32 + l31) * 64];
      int rx = (dt * 32 + l31) & 7;
#pragma unroll
      for (int ks = 0; ks < 4; ++ks)
        vb[dt][ks] = *reinterpret_cast<const bf16x8*>(vbase + (((ks * 2 + hi) ^ rx) << 3));
    }

    f32x16 p4[2] = {};
    __builtin_amdgcn_s_setprio(1);
#pragma unroll
    for (int t = 0; t < 2; ++t)
#pragma unroll
      for (int ks = 0; ks < 4; ++ks)
        p4[t] = __builtin_amdgcn_mfma_f32_32x32x16_bf16(kb[t][ks], qb[ks], p4[t], 0, 0, 0);
    __builtin_amdgcn_s_setprio(0);

    float mx[8];
#pragma unroll
    for (int r = 0; r < 8; ++r)
      mx[r] = fmaxf(fmaxf(p4[0][r], p4[0][r + 8]), fmaxf(p4[1][r], p4[1][r + 8]));
#pragma unroll
    for (int s = 4; s > 0; s >>= 1)
#pragma unroll
      for (int r = 0; r < s; ++r) mx[r] = fmaxf(mx[r], mx[r + s]);
    float tmax = fmaxf(mx[0], __shfl_xor(mx[0], 32));

    if (__any(tmax > m_run + 11.0f)) {
      float mnew = fmaxf(m_run, tmax);
      float alpha = __builtin_amdgcn_exp2f(m_run - mnew);
      m_run = mnew;
      l_run *= alpha;
#pragma unroll
      for (int r = 0; r < 16; ++r) {
        float ab = __shfl(alpha, (r & 3) + 8 * (r >> 2) + 4 * hi);
        oacc[0][r] *= ab;
        oacc[1][r] *= ab;
      }
    }

    float rs = 0.f;
    u32 w[2][4][2];
#pragma unroll
    for (int t = 0; t < 2; ++t)
#pragma unroll
      for (int g = 0; g < 4; ++g) {
        float e0 = __builtin_amdgcn_exp2f(p4[t][4 * g + 0] - m_run);
        float e1 = __builtin_amdgcn_exp2f(p4[t][4 * g + 1] - m_run);
        float e2 = __builtin_amdgcn_exp2f(p4[t][4 * g + 2] - m_run);
        float e3 = __builtin_amdgcn_exp2f(p4[t][4 * g + 3] - m_run);
        rs += (e0 + e1) + (e2 + e3);
        w[t][g][0] = pack_bf2(e0, e1);
        w[t][g][1] = pack_bf2(e2, e3);
      }
    rs += __shfl_xor(rs, 32);
    l_run += rs;

    bf16x8 pa[4];
#pragma unroll
    for (int ks = 0; ks < 4; ++ks) {
      const int t = ks >> 1, q2 = (ks & 1) * 2;
      auto s0 = __builtin_amdgcn_permlane32_swap(w[t][q2][0], w[t][q2 + 1][0], false, false);
      auto s1 = __builtin_amdgcn_permlane32_swap(w[t][q2][1], w[t][q2 + 1][1], false, false);
      union { u32 u[4]; bf16x8 v; } cv;
      cv.u[0] = s0[0]; cv.u[1] = s1[0]; cv.u[2] = s0[1]; cv.u[3] = s1[1];
      pa[ks] = cv.v;
    }

    __builtin_amdgcn_s_setprio(1);
#pragma unroll
    for (int ks = 0; ks < 4; ++ks) {
      oacc[0] = __builtin_amdgcn_mfma_f32_32x32x16_bf16(pa[ks], vb[0][ks], oacc[0], 0, 0, 0);
      oacc[1] = __builtin_amdgcn_mfma_f32_32x32x16_bf16(pa[ks], vb[1][ks], oacc[1], 0, 0, 0);
    }
    __builtin_amdgcn_s_setprio(0);

    asm volatile("" ::: "memory");
    __builtin_amdgcn_s_barrier();
  }

  float linv = __builtin_amdgcn_rcpf(l_run);
  const size_t orow0 = bq + q0 + wave * 32;
#pragma unroll
  for (int r = 0; r < 16; ++r) {
    int qr = (r & 3) + 8 * (r >> 2) + 4 * hi;
    float li = __shfl(linv, qr);
    size_t rb = (orow0 + qr) * 1024 + hc + l31;
    Oa[rb]      = f2bf(oacc[0][r] * li);
    Oa[rb + 32] = f2bf(oacc[1][r] * li);
  }
}

// ---------------- GEMM2: out[8192][1024] = Oa @ Wout^T + b_out (fp32) ----------------
// 256x128 tile, grid 256 = 1 pass over all CUs.
__global__ __launch_bounds__(512, 2)
void k_gemm_out(const u16* __restrict__ Ob, const u16* __restrict__ Wb,
                const float* __restrict__ bout, float* __restrict__ out) {
  __shared__ u16 SH[49152];
  const int tid = threadIdx.x, lane = tid & 63, wave = tid >> 6;
  const int lr = lane & 15, lg = (lane >> 4) & 3;
  const int wr = wave >> 1, wc = wave & 1;
  const int wg = blockIdx.x;
  const int swz = (wg & 7) * 32 + (wg >> 3);        // bijective: 256 % 8 == 0
  const int m0 = (swz >> 3) * 256, n0 = (swz & 7) * 128;

  auto stage = [&](int kt, int bb) {
    const int k0 = kt * 64;
    const int r8 = tid >> 3, ch = tid & 7;
#pragma unroll
    for (int i = 0; i < 4; ++i) {
      int row = i * 64 + r8;
      int gc = (ch ^ (row & 7)) << 3;
      GLDS16(Ob + (size_t)(m0 + row) * 1024 + k0 + gc, &SH[bb * 16384 + (i * 64 + wave * 8) * 64]);
    }
#pragma unroll
    for (int i = 0; i < 2; ++i) {
      int row = i * 64 + r8;
      int gc = (ch ^ (row & 7)) << 3;
      GLDS16(Wb + (size_t)(n0 + row) * 1024 + k0 + gc,
             &SH[32768 + bb * 8192 + (i * 64 + wave * 8) * 64]);
    }
  };

  f32x4 acc[4][4] = {};
  stage(0, 0);
  stage(1, 1);
  asm volatile("s_waitcnt vmcnt(6)" ::: "memory");
  __builtin_amdgcn_s_barrier();

  for (int kt = 0; kt < 16; ++kt) {
    const int cur = kt & 1;
    const u16* Ab = &SH[cur * 16384];
    const u16* Bb = &SH[32768 + cur * 8192];
    bf16x8 afr[4][2], bfr[4][2];
#pragma unroll
    for (int mi = 0; mi < 4; ++mi)
#pragma unroll
      for (int kk = 0; kk < 2; ++kk)
        afr[mi][kk] = *reinterpret_cast<const bf16x8*>(
            &Ab[(wr * 64 + mi * 16 + lr) * 64 + (((kk * 4 + lg) ^ (lr & 7)) << 3)]);
#pragma unroll
    for (int ni = 0; ni < 4; ++ni)
#pragma unroll
      for (int kk = 0; kk < 2; ++kk)
        bfr[ni][kk] = *reinterpret_cast<const bf16x8*>(
            &Bb[(wc * 64 + ni * 16 + lr) * 64 + (((kk * 4 + lg) ^ (lr & 7)) << 3)]);
    __builtin_amdgcn_s_setprio(1);
#pragma unroll
    for (int mi = 0; mi < 4; ++mi)
#pragma unroll
      for (int ni = 0; ni < 4; ++ni)
#pragma unroll
        for (int kk = 0; kk < 2; ++kk)
          acc[mi][ni] = __builtin_amdgcn_mfma_f32_16x16x32_bf16(
              afr[mi][kk], bfr[ni][kk], acc[mi][ni], 0, 0, 0);
    __builtin_amdgcn_s_setprio(0);
    if (kt == 15) break;
    __builtin_amdgcn_s_barrier();
    if (kt + 2 < 16) {
      stage(kt + 2, cur);
      asm volatile("s_waitcnt vmcnt(6)" ::: "memory");
    } else {
      asm volatile("s_waitcnt vmcnt(0)" ::: "memory");
    }
    __builtin_amdgcn_s_barrier();
  }

#pragma unroll
  for (int mi = 0; mi < 4; ++mi) {
    int row = m0 + wr * 64 + mi * 16 + (lg << 2);
#pragma unroll
    for (int ni = 0; ni < 4; ++ni) {
      int col = n0 + wc * 64 + ni * 16 + lr;
      float bias = bout[col];
#pragma unroll
      for (int j = 0; j < 4; ++j)
        out[(size_t)(row + j) * 1024 + col] = acc[mi][ni][j] + bias;
    }
  }
}

extern "C" void kernel_launch(void* const* d_in, const int* in_sizes, int n_in,
                              void* d_out, int out_size, void* d_ws, size_t ws_size,
                              hipStream_t stream) {
  const float* x     = (const float*)d_in[0];
  const float* Wqkv  = (const float*)d_in[1];
  const float* Wlora = (const float*)d_in[2];
  const float* blora = (const float*)d_in[3];
  const float* Aq    = (const float*)d_in[4];
  const float* Bq    = (const float*)d_in[5];
  const float* Av    = (const float*)d_in[6];
  const float* Bv    = (const float*)d_in[7];
  const float* Wout  = (const float*)d_in[8];
  const float* bout  = (const float*)d_in[9];
  float* out = (float*)d_out;

  char* w = (char*)d_ws;
  auto alloc = [&](size_t bytes) { char* p = w; w += (bytes + 255) & ~(size_t)255; return p; };
  u16*   Xb    = (u16*)alloc((size_t)8192 * 1024 * 2);   // x bf16  (reused as Oa later)
  u16*   Weff  = (u16*)alloc((size_t)3072 * 1024 * 2);
  float* beff  = (float*)alloc((size_t)3072 * 4);
  u16*   Woutb = (u16*)alloc((size_t)1024 * 1024 * 2);
  u16*   Y     = (u16*)alloc((size_t)8192 * 3072 * 2);   // qkv (q pre-scaled by log2e/8)
  u16*   Vt    = (u16*)alloc((size_t)4096 * 1024 * 2 * 2); // [(b*16+h)*64+d][2048] bf16
  u16*   Oa    = Xb;  // alias: Xb is dead after GEMM1

  k_prep<<<dim3(21504), dim3(256), 0, stream>>>(x, Wqkv, Wlora, blora, Aq, Bq, Av, Bv, Wout,
                                                Xb, Weff, beff, Woutb);
  k_gemm_qkv<<<dim3(768), dim3(512), 0, stream>>>(Xb, Weff, beff, Y, Vt);
  k_attn<<<dim3(16, 64), dim3(256), 0, stream>>>(Y, Vt, Oa);
  k_gemm_out<<<dim3(256), dim3(512), 0, stream>>>(Oa, Woutb, bout, out);
}